// Round 3
// baseline (484.792 us; speedup 1.0000x reference)
//
#include <hip/hip_runtime.h>
#include <hip/hip_bf16.h>

// Problem: B=256, N=512, adjacency fp32 [B,N,N].
// out[b,i,j] = dinv[b,i] * a_hat[b,i,j] * dinv[b,j]
//   a_hat = adjacency with diagonal replaced by mask = (rowsum != 0)
//   deg   = rowsum - diag + mask   (entries 0/1 -> exact in fp32)
//   dinv  = deg > 0 ? 1/sqrt(deg) : 0
// Diagonal output = dinv_i * 1.0 * dinv_i (mask=0 => dinv=0), so phase B just
// substitutes a=1 on the diagonal; mask itself is never needed downstream.
//
// Fused design: one workgroup per batch. Phase A computes the 512 row degrees
// into LDS (reads the batch's 1 MiB); phase B immediately re-reads the same
// 1 MiB (hot in L2/L3), scales, writes with nontemporal stores (don't evict
// the input from L3 with the write stream).

#define NN 512    // N
#define NB 256    // B

typedef float f32x4 __attribute__((ext_vector_type(4)));  // native vec for builtins

__global__ __launch_bounds__(1024) void fused_norm_kernel(
    const float* __restrict__ adj, float* __restrict__ out) {
    __shared__ float sdinv[NN];

    const int b = blockIdx.x;
    const size_t base4 = (size_t)b * (NN * (NN / 4));   // float4 index base
    const f32x4* a4 = (const f32x4*)adj + base4;
    f32x4*       o4 = (f32x4*)out + base4;

    const int tid  = threadIdx.x;
    const int wave = tid >> 6;      // 0..15
    const int lane = tid & 63;

    // ---- Phase A: row degrees. One row per wave per iteration (32 iters). ----
    for (int rr = 0; rr < 32; ++rr) {
        const int row = wave * 32 + rr;
        const f32x4* r4 = a4 + row * (NN / 4);
        f32x4 x0 = r4[lane];          // cols [lane*4, lane*4+4)
        f32x4 x1 = r4[lane + 64];     // cols [256+lane*4, ...)

        float s = (x0.x + x0.y) + (x0.z + x0.w) + (x1.x + x1.y) + (x1.z + x1.w);

        // diagonal element: column index == row (within batch)
        float diag = 0.0f;
        int j0 = lane << 2;
        if (row >= j0 && row < j0 + 4) diag = ((const float*)&x0)[row - j0];
        int j1 = 256 + (lane << 2);
        if (row >= j1 && row < j1 + 4) diag = ((const float*)&x1)[row - j1];

        #pragma unroll
        for (int off = 32; off > 0; off >>= 1) {
            s    += __shfl_xor(s, off);
            diag += __shfl_xor(diag, off);
        }
        if (lane == 0) {
            float mask = (s != 0.0f) ? 1.0f : 0.0f;
            float deg  = s - diag + mask;
            sdinv[row] = (deg > 0.0f) ? (1.0f / sqrtf(deg)) : 0.0f;
        }
    }
    __syncthreads();

    // ---- Phase B: scale + write. j4 is loop-invariant per thread, so dj
    // lives in registers; di is an LDS broadcast (wave-uniform per 128 thr). ----
    const int j4    = tid & 127;       // float4 column index, fixed per thread
    const int rbase = tid >> 7;        // 0..7
    const f32x4 dj = ((const f32x4*)sdinv)[j4];
    const int jj = j4 << 2;

    // reverse row order: freshest cache lines from phase A first
    for (int it = 63; it >= 0; --it) {
        const int row = rbase + (it << 3);
        const float di = sdinv[row];
        const size_t k = (size_t)row * (NN / 4) + j4;
        f32x4 a = a4[k];
        f32x4 o;
        // reference order: (dinv_i * a_hat) * dinv_j
        o.x = (di * ((jj + 0 == row) ? 1.0f : a.x)) * dj.x;
        o.y = (di * ((jj + 1 == row) ? 1.0f : a.y)) * dj.y;
        o.z = (di * ((jj + 2 == row) ? 1.0f : a.z)) * dj.z;
        o.w = (di * ((jj + 3 == row) ? 1.0f : a.w)) * dj.w;
        __builtin_nontemporal_store(o, &o4[k]);
    }
}

extern "C" void kernel_launch(void* const* d_in, const int* in_sizes, int n_in,
                              void* d_out, int out_size, void* d_ws, size_t ws_size,
                              hipStream_t stream) {
    const float* adj = (const float*)d_in[0];
    float* out = (float*)d_out;
    // one workgroup per batch
    fused_norm_kernel<<<NB, 1024, 0, stream>>>(adj, out);
}

// Round 4
// 458.071 us; speedup vs baseline: 1.0583x; 1.0583x over previous
//
#include <hip/hip_runtime.h>
#include <hip/hip_bf16.h>

// Problem: B=256, N=512, adjacency fp32 [B,N,N].
// out[b,i,j] = dinv[b,i] * a_hat[b,i,j] * dinv[b,j]
//   a_hat = adjacency with diagonal replaced by mask = (rowsum != 0)
//   deg   = rowsum - diag + mask   (entries 0/1 -> exact in fp32)
//   dinv  = deg > 0 ? 1/sqrt(deg) : 0
// Diagonal output = dinv_i * 1.0 * dinv_i (mask=0 => dinv=0).
//
// Round-3 lesson: block-scope fusion (1 wg/batch) is latency-bound (196 us).
// The reuse between the two passes lives at L3 scope (input = 256 MiB = L3
// capacity). So: split kernels; pass 1 reads forward and leaves input in L3;
// pass 2 walks in REVERSE block order (freshest lines first — LRU at exact
// capacity punishes same-order re-traversal) and writes the output with
// NONTEMPORAL stores so the 256 MiB write stream doesn't evict the input.

#define NN 512    // N
#define NB 256    // B

typedef float f32x4 __attribute__((ext_vector_type(4)));  // native vec for builtins

// Pass 1: one 64-lane wave per row; 2 float4 loads/lane; butterfly reduce
// rowsum + diagonal; write dinv.
__global__ __launch_bounds__(256) void degree_kernel(
    const float* __restrict__ adj, float* __restrict__ dinv) {
    int gtid = blockIdx.x * blockDim.x + threadIdx.x;
    int row  = gtid >> 6;           // wave index == global row index
    int lane = threadIdx.x & 63;

    const f32x4* r4 = (const f32x4*)(adj + (size_t)row * NN);
    f32x4 a0 = r4[lane];            // cols [lane*4, lane*4+4)
    f32x4 a1 = r4[lane + 64];       // cols [256+lane*4, ...)

    float s = (a0.x + a0.y) + (a0.z + a0.w) + (a1.x + a1.y) + (a1.z + a1.w);

    int i = row & (NN - 1);         // diagonal column (within batch)
    float diag = 0.0f;
    int j0 = lane << 2;
    if (i >= j0 && i < j0 + 4) diag = ((const float*)&a0)[i - j0];
    int j1 = 256 + (lane << 2);
    if (i >= j1 && i < j1 + 4) diag = ((const float*)&a1)[i - j1];

    #pragma unroll
    for (int off = 32; off > 0; off >>= 1) {
        s    += __shfl_xor(s, off);
        diag += __shfl_xor(diag, off);
    }

    if (lane == 0) {
        float mask = (s != 0.0f) ? 1.0f : 0.0f;
        float deg  = s - diag + mask;
        dinv[row]  = (deg > 0.0f) ? (1.0f / sqrtf(deg)) : 0.0f;
    }
}

// Pass 2: one thread per output float4. Reverse block order (L3 freshness),
// temporal loads (hit L3), nontemporal stores (don't pollute L3).
__global__ __launch_bounds__(256) void scale_kernel(
    const float* __restrict__ adj, const float* __restrict__ dinv,
    float* __restrict__ out, unsigned numBlocks) {
    unsigned rb = numBlocks - 1u - blockIdx.x;          // reversed block index
    size_t idx4 = (size_t)rb * blockDim.x + threadIdx.x;

    int    j4   = (int)(idx4 & 127);        // float4 column (N/4 = 128)
    size_t row  = idx4 >> 7;                // global row in [0, B*N)
    int    i    = (int)(row & (NN - 1));    // diagonal column
    size_t rowb = row & ~(size_t)(NN - 1);  // b*N

    f32x4 a  = ((const f32x4*)adj)[idx4];
    f32x4 dj = ((const f32x4*)(dinv + rowb))[j4];
    float di = dinv[row];

    int j = j4 << 2;
    // reference order: (dinv_i * a_hat) * dinv_j
    f32x4 o;
    o.x = (di * ((j + 0 == i) ? 1.0f : a.x)) * dj.x;
    o.y = (di * ((j + 1 == i) ? 1.0f : a.y)) * dj.y;
    o.z = (di * ((j + 2 == i) ? 1.0f : a.z)) * dj.z;
    o.w = (di * ((j + 3 == i) ? 1.0f : a.w)) * dj.w;

    __builtin_nontemporal_store(o, &((f32x4*)out)[idx4]);
}

extern "C" void kernel_launch(void* const* d_in, const int* in_sizes, int n_in,
                              void* d_out, int out_size, void* d_ws, size_t ws_size,
                              hipStream_t stream) {
    const float* adj = (const float*)d_in[0];
    float* out  = (float*)d_out;
    float* dinv = (float*)d_ws;            // B*N floats = 512 KiB scratch

    const int totalRows = NB * NN;         // 131072 rows, 1 wave each
    degree_kernel<<<totalRows / 4, 256, 0, stream>>>(adj, dinv);

    const size_t total4 = (size_t)NB * NN * NN / 4;     // 16,777,216
    const unsigned nblk = (unsigned)(total4 / 256);     // 65536
    scale_kernel<<<nblk, 256, 0, stream>>>(adj, dinv, out, nblk);
}